// Round 11
// baseline (575.547 us; speedup 1.0000x reference)
//
#include <hip/hip_runtime.h>

// Problem constants (B=16, N=4096, C=64, O=64, D=16, K=3)
#define NN 4096
#define DD 16
#define BB 16
#define CC 64
#define OO 64
#define BC 1024   // BB*CC

typedef unsigned short u16;
typedef unsigned int u32;
typedef __attribute__((ext_vector_type(8))) short bf16x8;
typedef __attribute__((ext_vector_type(4))) float f32x4;

__device__ __forceinline__ u16 f2bf(float f) {
    unsigned u = __builtin_bit_cast(unsigned, f);
    unsigned r = u + 0x7FFFu + ((u >> 16) & 1u);
    return (u16)(r >> 16);
}
__device__ __forceinline__ float bf2f(u16 h) {
    unsigned u = ((unsigned)h) << 16;
    return __builtin_bit_cast(float, u);
}

// ---------------------------------------------------------------------------
// Kernel 1: A = softmax(relu(E @ E^T), axis=1) -> split bf16 (Ah + Al)
// ---------------------------------------------------------------------------
__global__ __launch_bounds__(256) void softmax_adj(const float* __restrict__ E,
                                                   u16* __restrict__ Ah,
                                                   u16* __restrict__ Al) {
    const int i = blockIdx.x;
    const int t = threadIdx.x;
    __shared__ float esh[DD];
    __shared__ float redm[4], reds[4];
    if (t < DD) esh[t] = E[i * DD + t];
    __syncthreads();
    float er[DD];
#pragma unroll
    for (int d = 0; d < DD; ++d) er[d] = esh[d];

    float v[16];
    float m = 0.0f;  // relu => max >= 0
#pragma unroll
    for (int s = 0; s < 16; ++s) {
        const int j = s * 256 + t;
        const float4* ej = (const float4*)(E + j * DD);
        float4 a0 = ej[0], a1 = ej[1], a2 = ej[2], a3 = ej[3];
        float dot = a0.x * er[0] + a0.y * er[1] + a0.z * er[2] + a0.w * er[3]
                  + a1.x * er[4] + a1.y * er[5] + a1.z * er[6] + a1.w * er[7]
                  + a2.x * er[8] + a2.y * er[9] + a2.z * er[10] + a2.w * er[11]
                  + a3.x * er[12] + a3.y * er[13] + a3.z * er[14] + a3.w * er[15];
        v[s] = fmaxf(dot, 0.0f);
        m = fmaxf(m, v[s]);
    }
#pragma unroll
    for (int off = 1; off < 64; off <<= 1) m = fmaxf(m, __shfl_xor(m, off));
    const int wave = t >> 6, lane = t & 63;
    if (lane == 0) redm[wave] = m;
    __syncthreads();
    m = fmaxf(fmaxf(redm[0], redm[1]), fmaxf(redm[2], redm[3]));

    float sum = 0.0f;
#pragma unroll
    for (int s = 0; s < 16; ++s) {
        v[s] = expf(v[s] - m);
        sum += v[s];
    }
#pragma unroll
    for (int off = 1; off < 64; off <<= 1) sum += __shfl_xor(sum, off);
    if (lane == 0) reds[wave] = sum;
    __syncthreads();
    const float rinv = 1.0f / (reds[0] + reds[1] + reds[2] + reds[3]);
#pragma unroll
    for (int s = 0; s < 16; ++s) {
        const float val = v[s] * rinv;
        const u16 hh = f2bf(val);
        Ah[(size_t)i * NN + s * 256 + t] = hh;
        Al[(size_t)i * NN + s * 256 + t] = f2bf(val - bf2f(hh));
    }
}

// ---------------------------------------------------------------------------
// Kernel 2: transpose+split X [B,N,C] -> Xt_{h,l} [BC=b*64+c][N] bf16
// ---------------------------------------------------------------------------
__global__ __launch_bounds__(256) void pack_xt(const float* __restrict__ X,
                                               u16* __restrict__ Xth,
                                               u16* __restrict__ Xtl) {
    const int n0 = blockIdx.x * 64;
    const int b  = blockIdx.y;
    const int t  = threadIdx.x;
    __shared__ float tx[64][68];
    const float* src = X + (size_t)b * (NN * CC) + (size_t)n0 * CC;
#pragma unroll
    for (int l = 0; l < 4; ++l) {
        const int idx = t + l * 256;   // 1024 float4 chunks
        const int r = idx >> 4;
        const int c4 = (idx & 15) * 4;
        float4 v = *(const float4*)(src + r * CC + c4);
        tx[r][c4 + 0] = v.x; tx[r][c4 + 1] = v.y;
        tx[r][c4 + 2] = v.z; tx[r][c4 + 3] = v.w;
    }
    __syncthreads();
#pragma unroll
    for (int l = 0; l < 2; ++l) {
        const int idx = t + l * 256;   // 512 chunks of 8 bf16
        const int c = idx >> 3;
        const int n8 = (idx & 7) * 8;
        unsigned hw[4], lw[4];
#pragma unroll
        for (int jp = 0; jp < 4; ++jp) {
            float v0 = tx[n8 + 2 * jp][c];
            float v1 = tx[n8 + 2 * jp + 1][c];
            u16 h0 = f2bf(v0), h1 = f2bf(v1);
            u16 l0 = f2bf(v0 - bf2f(h0)), l1 = f2bf(v1 - bf2f(h1));
            hw[jp] = (unsigned)h0 | ((unsigned)h1 << 16);
            lw[jp] = (unsigned)l0 | ((unsigned)l1 << 16);
        }
        const size_t off = (size_t)(b * 64 + c) * NN + n0 + n8;
        *(uint4*)(Xth + off) = make_uint4(hw[0], hw[1], hw[2], hw[3]);
        *(uint4*)(Xtl + off) = make_uint4(lw[0], lw[1], lw[2], lw[3]);
    }
}

// ---------------------------------------------------------------------------
// Kernel 3: split-bf16 MFMA GEMM. Tile 256x128, 4-way K-SPLIT (K=1024/block),
//   512 threads (8 waves 4Mx2N, 64x64/wave), SINGLE-buffer LDS 48KB
//   -> 512 blocks = 2 blocks/CU: anti-phase block overlap (rd10-proven 8.6TB/s)
//   at -28% staged traffic (768MB vs 1.07GB). Partials P0..P2 + d_out (P3).
// ---------------------------------------------------------------------------
#define GLOAD16(g, l) __builtin_amdgcn_global_load_lds( \
    (const __attribute__((address_space(1))) unsigned int*)(g), \
    (__attribute__((address_space(3))) unsigned int*)(l), 16, 0, 0)

__global__ __launch_bounds__(512) void gemm_ks(
    const u16* __restrict__ Ah, const u16* __restrict__ Al,
    const u16* __restrict__ Bh, const u16* __restrict__ Bl,
    float* __restrict__ P0, float* __restrict__ P1,
    float* __restrict__ P2, float* __restrict__ P3)
{
    // uint4 chunks: [Ah 0..1023][Al 1024..2047][Bh 2048..2559][Bl 2560..3071]
    __shared__ uint4 lds[3072];   // 48 KB single buffer
    const int t = threadIdx.x;

    const int lin  = blockIdx.x;
    const int col0 = (lin & 7) * 128;           // 8 col panels = XCD id (rr)
    const int row0 = ((lin >> 3) & 15) * 256;   // 16 M panels
    const int kq   = lin >> 7;                  // 0..3 K-quarter
    const int kbase = kq * 1024;
    float* __restrict__ Pf = (kq & 2) ? ((kq & 1) ? P3 : P2)
                                      : ((kq & 1) ? P1 : P0);

    // staging: chunk j -> row=j>>2, slot=j&3; source slot inverse-swizzled.
    // A: 1024 chunks/array (rows 0..255): thread handles j0=t, j1=t+512.
    // B: 512 chunks/array (rows 0..127): thread handles jb=t.
    const int j0 = t, j1 = t + 512;
    const int r0 = j0 >> 2;                    // j1 row = r0+128, same slot
    const int s0 = (j0 & 3) ^ ((j0 >> 3) & 3);
    const size_t aoff0 = (size_t)(row0 + r0) * NN + 8 * s0 + kbase;
    const size_t aoff1 = (size_t)(row0 + r0 + 128) * NN + 8 * s0 + kbase;
    const size_t boff0 = (size_t)(col0 + r0) * NN + 8 * s0 + kbase;

    const int lane = t & 63, g = lane >> 4, lr = lane & 15;
    const int wm = t >> 7;            // 0..3
    const int wn = (t >> 6) & 1;      // 0..1
    int ia[4], ib[4];
#pragma unroll
    for (int i = 0; i < 4; ++i) {
        const int ra = wm * 64 + 16 * i + lr;
        ia[i] = ra * 4 + (g ^ ((ra >> 1) & 3));
        const int rb = wn * 64 + 16 * i + lr;
        ib[i] = rb * 4 + (g ^ ((rb >> 1) & 3));
    }

    f32x4 acc[4][4];
    const f32x4 zz = {0.f, 0.f, 0.f, 0.f};
#pragma unroll
    for (int i = 0; i < 4; ++i)
#pragma unroll
        for (int p = 0; p < 4; ++p) acc[i][p] = zz;

#define STAGE(kt) do { \
        GLOAD16(Ah + aoff0 + (kt), &lds[j0]); \
        GLOAD16(Ah + aoff1 + (kt), &lds[j1]); \
        GLOAD16(Al + aoff0 + (kt), &lds[1024 + j0]); \
        GLOAD16(Al + aoff1 + (kt), &lds[1024 + j1]); \
        GLOAD16(Bh + boff0 + (kt), &lds[2048 + j0]); \
        GLOAD16(Bl + boff0 + (kt), &lds[2560 + j0]); \
    } while (0)

    STAGE(0);

#pragma unroll 2
    for (int kt = 0; kt < 1024; kt += 32) {
        __syncthreads();   // drains own vmcnt -> staged data landed for all

        bf16x8 ah[4], al[4], bh[4], bl[4];
#pragma unroll
        for (int i = 0; i < 4; ++i) {
            ah[i] = *(const bf16x8*)&lds[ia[i]];
            al[i] = *(const bf16x8*)&lds[1024 + ia[i]];
            bh[i] = *(const bf16x8*)&lds[2048 + ib[i]];
            bl[i] = *(const bf16x8*)&lds[2560 + ib[i]];
        }
#pragma unroll
        for (int i = 0; i < 4; ++i)
#pragma unroll
            for (int p = 0; p < 4; ++p) {
                acc[i][p] = __builtin_amdgcn_mfma_f32_16x16x32_bf16(ah[i], bh[p], acc[i][p], 0, 0, 0);
                acc[i][p] = __builtin_amdgcn_mfma_f32_16x16x32_bf16(ah[i], bl[p], acc[i][p], 0, 0, 0);
                acc[i][p] = __builtin_amdgcn_mfma_f32_16x16x32_bf16(al[i], bh[p], acc[i][p], 0, 0, 0);
            }
        __syncthreads();   // all waves done reading -> safe to overwrite
        if (kt + 32 < 1024) STAGE(kt + 32);
    }

    // epilogue: f32 partial. C/D layout col=lane&15, row=(lane>>4)*4+q.
#pragma unroll
    for (int i = 0; i < 4; ++i)
#pragma unroll
        for (int p = 0; p < 4; ++p) {
            const int mb = row0 + wm * 64 + 16 * i + g * 4;
            const int c  = col0 + wn * 64 + 16 * p + lr;
#pragma unroll
            for (int q = 0; q < 4; ++q)
                Pf[(size_t)(mb + q) * BC + c] = acc[i][p][q];
        }
#undef STAGE
}

// ---------------------------------------------------------------------------
// Kernel 3b: sum 4 partials + transpose-split -> G1t_{h,l} (into Xt slots).
//   No f32 G1 materialized (final_apply reads the G1th slice directly).
// ---------------------------------------------------------------------------
__global__ __launch_bounds__(256) void reduce_t4(const float* __restrict__ P0,
                                                 const float* __restrict__ P1,
                                                 const float* __restrict__ P2,
                                                 const float* __restrict__ P3,
                                                 u16* __restrict__ G1th,
                                                 u16* __restrict__ G1tl) {
    const int n0 = blockIdx.x * 64;
    const int c0 = blockIdx.y * 64;
    const int t  = threadIdx.x;
    __shared__ float tx[64][68];
#pragma unroll
    for (int l = 0; l < 4; ++l) {
        const int idx = t + l * 256;
        const int r = idx >> 4;
        const int c4 = (idx & 15) * 4;
        const size_t off = (size_t)(n0 + r) * BC + c0 + c4;
        float4 v0 = *(const float4*)(P0 + off);
        float4 v1 = *(const float4*)(P1 + off);
        float4 v2 = *(const float4*)(P2 + off);
        float4 v3 = *(const float4*)(P3 + off);
        tx[r][c4 + 0] = (v0.x + v1.x) + (v2.x + v3.x);
        tx[r][c4 + 1] = (v0.y + v1.y) + (v2.y + v3.y);
        tx[r][c4 + 2] = (v0.z + v1.z) + (v2.z + v3.z);
        tx[r][c4 + 3] = (v0.w + v1.w) + (v2.w + v3.w);
    }
    __syncthreads();
#pragma unroll
    for (int l = 0; l < 2; ++l) {
        const int idx = t + l * 256;
        const int c = idx >> 3;
        const int n8 = (idx & 7) * 8;
        unsigned hw[4], lw[4];
#pragma unroll
        for (int jp = 0; jp < 4; ++jp) {
            float v0 = tx[n8 + 2 * jp][c];
            float v1 = tx[n8 + 2 * jp + 1][c];
            u16 h0 = f2bf(v0), h1 = f2bf(v1);
            u16 l0 = f2bf(v0 - bf2f(h0)), l1 = f2bf(v1 - bf2f(h1));
            hw[jp] = (unsigned)h0 | ((unsigned)h1 << 16);
            lw[jp] = (unsigned)l0 | ((unsigned)l1 << 16);
        }
        const size_t off = (size_t)(c0 + c) * NN + n0 + n8;
        *(uint4*)(G1th + off) = make_uint4(hw[0], hw[1], hw[2], hw[3]);
        *(uint4*)(G1tl + off) = make_uint4(lw[0], lw[1], lw[2], lw[3]);
    }
}

// ---------------------------------------------------------------------------
// Kernel 3c: G2f = P0+P1+P2+P3, written in-place into P0.
// ---------------------------------------------------------------------------
__global__ __launch_bounds__(256) void reduce_lin4(float* __restrict__ P0,
                                                   const float* __restrict__ P1,
                                                   const float* __restrict__ P2,
                                                   const float* __restrict__ P3) {
    const int idx = blockIdx.x * 256 + threadIdx.x;   // NN*BC/4 float4s
    float4 a = ((const float4*)P0)[idx];
    float4 b = ((const float4*)P1)[idx];
    float4 c = ((const float4*)P2)[idx];
    float4 d = ((const float4*)P3)[idx];
    ((float4*)P0)[idx] = make_float4((a.x + b.x) + (c.x + d.x),
                                     (a.y + b.y) + (c.y + d.y),
                                     (a.z + b.z) + (c.z + d.z),
                                     (a.w + b.w) + (c.w + d.w));
}

// ---------------------------------------------------------------------------
// Kernel 4: 4 nodes x 32-o-half per block, 512 threads (rd10 structure).
//   G1 now read as bf16-hi slice from G1th[bc][n] (same value as f2bf(G1f)).
// ---------------------------------------------------------------------------
__global__ __launch_bounds__(512) void final_apply3(const float* __restrict__ X,
                                                    const float* __restrict__ E,
                                                    const u16* __restrict__ G1th,
                                                    const float* __restrict__ G2,
                                                    const float* __restrict__ wp,
                                                    const float* __restrict__ bp,
                                                    float* __restrict__ out) {
    const int ng = blockIdx.x;         // nodes ng*4 .. ng*4+3
    const int oh = blockIdx.y;         // o-half
    const int o0 = oh * 32;
    const int t  = threadIdx.x;
    __shared__ float Wl[4][192][32];       // 98304 B
    __shared__ u16   xgb[4][3][16][68];    // 26112 B
    __shared__ float esh[4][16];

    if (t < 64) esh[t >> 4][t & 15] = E[(ng * 4 + (t >> 4)) * DD + (t & 15)];

    // ---- stage xg k=0 (X) and k=2 (2*G2-X): 2048 float4-chunks, 4/thread ----
#pragma unroll
    for (int l = 0; l < 4; ++l) {
        const int c = t + l * 512;
        const int kk = c >> 10;          // 0: X, 1: G2-branch
        const int j  = (c >> 8) & 3;
        const int b  = (c >> 4) & 15;
        const int i4 = c & 15;
        const int n_g = ng * 4 + j;
        float4 v;
        if (kk == 0) {
            v = *(const float4*)(X + ((size_t)b * NN + n_g) * CC + i4 * 4);
        } else {
            float4 g2 = *(const float4*)(G2 + (size_t)n_g * BC + b * 64 + i4 * 4);
            float4 x  = *(const float4*)(X + ((size_t)b * NN + n_g) * CC + i4 * 4);
            v = make_float4(2.f * g2.x - x.x, 2.f * g2.y - x.y,
                            2.f * g2.z - x.z, 2.f * g2.w - x.w);
        }
        const int ks = (kk == 0) ? 0 : 2;
        u32 w0 = (u32)f2bf(v.x) | ((u32)f2bf(v.y) << 16);
        u32 w1 = (u32)f2bf(v.z) | ((u32)f2bf(v.w) << 16);
        *(uint2*)&xgb[j][ks][b][i4 * 4] = make_uint2(w0, w1);
    }
    // ---- stage xg k=1: G1th slice [bc][4ng..4ng+3], 1024 rows, 2/thread ----
#pragma unroll
    for (int l = 0; l < 2; ++l) {
        const int row = t + l * 512;     // bc = b*64 + i
        const int b = row >> 6;
        const int i = row & 63;
        const ushort4 g = *(const ushort4*)(G1th + (size_t)row * NN + 4 * ng);
        xgb[0][1][b][i] = g.x;
        xgb[1][1][b][i] = g.y;
        xgb[2][1][b][i] = g.z;
        xgb[3][1][b][i] = g.w;
    }
    __syncthreads();

    // ---- W-gen: 1536 (ki,o4) tasks, 3/thread; wp read ONCE for 4 nodes ----
    float er[4][16];
#pragma unroll
    for (int j = 0; j < 4; ++j)
#pragma unroll
        for (int d = 0; d < DD; ++d) er[j][d] = esh[j][d];

    const float4* wp4 = (const float4*)wp;
#pragma unroll
    for (int l = 0; l < 3; ++l) {
        const int tk = t + l * 512;
        const int ki = tk >> 3;          // 0..191
        const int q  = tk & 7;
        float4 a0 = make_float4(0.f, 0.f, 0.f, 0.f);
        float4 a1 = a0, a2 = a0, a3 = a0;
#pragma unroll
        for (int d = 0; d < DD; ++d) {
            float4 v = wp4[d * 3072 + ki * 16 + oh * 8 + q];
            a0.x += er[0][d] * v.x; a0.y += er[0][d] * v.y; a0.z += er[0][d] * v.z; a0.w += er[0][d] * v.w;
            a1.x += er[1][d] * v.x; a1.y += er[1][d] * v.y; a1.z += er[1][d] * v.z; a1.w += er[1][d] * v.w;
            a2.x += er[2][d] * v.x; a2.y += er[2][d] * v.y; a2.z += er[2][d] * v.z; a2.w += er[2][d] * v.w;
            a3.x += er[3][d] * v.x; a3.y += er[3][d] * v.y; a3.z += er[3][d] * v.z; a3.w += er[3][d] * v.w;
        }
        *(float4*)&Wl[0][ki][q * 4] = a0;
        *(float4*)&Wl[1][ki][q * 4] = a1;
        *(float4*)&Wl[2][ki][q * 4] = a2;
        *(float4*)&Wl[3][ki][q * 4] = a3;
    }
    __syncthreads();

    // ---- apply: thread -> (n = t>>7, b = (t>>3)&15, o4 = t&7) ----
    const int o4 = t & 7;
    const int b  = (t >> 3) & 15;
    const int n  = t >> 7;
    const int n_g = ng * 4 + n;

    const float4* bp4 = (const float4*)bp;
    float4 acc = make_float4(0.f, 0.f, 0.f, 0.f);
#pragma unroll
    for (int d = 0; d < DD; ++d) {
        const float e = esh[n][d];
        float4 bv = bp4[d * 16 + oh * 8 + o4];
        acc.x += e * bv.x; acc.y += e * bv.y; acc.z += e * bv.z; acc.w += e * bv.w;
    }
#pragma unroll
    for (int k = 0; k < 3; ++k) {
#pragma unroll
        for (int i2 = 0; i2 < 32; ++i2) {
            const u32 xu = *(const u32*)&xgb[n][k][b][i2 * 2];
            const float x0 = bf2f((u16)(xu & 0xffffu));
            const float x1 = bf2f((u16)(xu >> 16));
            const float4 w0 = *(const float4*)&Wl[n][k * 64 + i2 * 2][o4 * 4];
            const float4 w1 = *(const float4*)&Wl[n][k * 64 + i2 * 2 + 1][o4 * 4];
            acc.x += x0 * w0.x + x1 * w1.x;
            acc.y += x0 * w0.y + x1 * w1.y;
            acc.z += x0 * w0.z + x1 * w1.z;
            acc.w += x0 * w0.w + x1 * w1.w;
        }
    }
    *(float4*)(out + ((size_t)b * NN + n_g) * OO + o0 + o4 * 4) = acc;
}

// ---------------------------------------------------------------------------
extern "C" void kernel_launch(void* const* d_in, const int* in_sizes, int n_in,
                              void* d_out, int out_size, void* d_ws, size_t ws_size,
                              hipStream_t stream) {
    const float* X  = (const float*)d_in[0];   // [16,4096,64]
    const float* E  = (const float*)d_in[1];   // [4096,16]
    const float* wp = (const float*)d_in[3];   // [16,3,64,64]
    const float* bp = (const float*)d_in[4];   // [16,64]
    float* out = (float*)d_out;                // [16,4096,64] = 16 MB

    // ws layout (128 MB total, same footprint as rd10):
    u16* Ah   = (u16*)d_ws;                        // 32 MB
    u16* Al   = Ah   + (size_t)NN * NN;            // 32 MB
    u16* Xth  = Al   + (size_t)NN * NN;            //  8 MB (-> G1th after reduce_t4)
    u16* Xtl  = Xth  + (size_t)BC * NN;            //  8 MB (-> G1tl)
    float* P0 = (float*)(Xtl + (size_t)BC * NN);   // 16 MB (-> G2f after reduce_lin4)
    float* P1 = P0 + (size_t)NN * BC;              // 16 MB
    float* P2 = P1 + (size_t)NN * BC;              // 16 MB
    float* Pd = out;                               // 16 MB: d_out doubles as 4th
                                                   //   partial (dead until final,
                                                   //   fully consumed by reduces)

    softmax_adj<<<NN, 256, 0, stream>>>(E, Ah, Al);
    pack_xt<<<dim3(NN / 64, BB), 256, 0, stream>>>(X, Xth, Xtl);
    // GEMM1: G1 = A @ Xt^T  (4 K-quarter partials -> transpose-split G1t)
    gemm_ks<<<512, 512, 0, stream>>>(Ah, Al, Xth, Xtl, P0, P1, P2, Pd);
    reduce_t4<<<dim3(NN / 64, BC / 64), 256, 0, stream>>>(P0, P1, P2, Pd, Xth, Xtl);
    // GEMM2: G2 = A @ G1t^T  (partial slots all free again)
    gemm_ks<<<512, 512, 0, stream>>>(Ah, Al, Xth, Xtl, P0, P1, P2, Pd);
    reduce_lin4<<<(NN * BC / 4) / 256, 256, 0, stream>>>(P0, P1, P2, Pd);
    final_apply3<<<dim3(NN / 4, 2), 512, 0, stream>>>(X, E, Xth, P0, wp, bp, out);
}

// Round 12
// 384.901 us; speedup vs baseline: 1.4953x; 1.4953x over previous
//
#include <hip/hip_runtime.h>

// Problem constants (B=16, N=4096, C=64, O=64, D=16, K=3)
#define NN 4096
#define DD 16
#define BB 16
#define CC 64
#define OO 64
#define BC 1024   // BB*CC

typedef unsigned short u16;
typedef unsigned int u32;
typedef __attribute__((ext_vector_type(8))) _Float16 f16x8;
typedef __attribute__((ext_vector_type(4))) float f32x4;

__device__ __forceinline__ u16 f2bf(float f) {
    unsigned u = __builtin_bit_cast(unsigned, f);
    unsigned r = u + 0x7FFFu + ((u >> 16) & 1u);
    return (u16)(r >> 16);
}
__device__ __forceinline__ float bf2f(u16 h) {
    unsigned u = ((unsigned)h) << 16;
    return __builtin_bit_cast(float, u);
}
__device__ __forceinline__ u16 f2h_bits(float f) {
    _Float16 h = (_Float16)f;
    return __builtin_bit_cast(u16, h);
}
__device__ __forceinline__ float h2f(u16 b) {
    return (float)__builtin_bit_cast(_Float16, b);
}

// ---------------------------------------------------------------------------
// Kernel 1: A = softmax(relu(E @ E^T), axis=1) -> fp16
// ---------------------------------------------------------------------------
__global__ __launch_bounds__(256) void softmax_adj(const float* __restrict__ E,
                                                   u16* __restrict__ Af) {
    const int i = blockIdx.x;
    const int t = threadIdx.x;
    __shared__ float esh[DD];
    __shared__ float redm[4], reds[4];
    if (t < DD) esh[t] = E[i * DD + t];
    __syncthreads();
    float er[DD];
#pragma unroll
    for (int d = 0; d < DD; ++d) er[d] = esh[d];

    float v[16];
    float m = 0.0f;  // relu => max >= 0
#pragma unroll
    for (int s = 0; s < 16; ++s) {
        const int j = s * 256 + t;
        const float4* ej = (const float4*)(E + j * DD);
        float4 a0 = ej[0], a1 = ej[1], a2 = ej[2], a3 = ej[3];
        float dot = a0.x * er[0] + a0.y * er[1] + a0.z * er[2] + a0.w * er[3]
                  + a1.x * er[4] + a1.y * er[5] + a1.z * er[6] + a1.w * er[7]
                  + a2.x * er[8] + a2.y * er[9] + a2.z * er[10] + a2.w * er[11]
                  + a3.x * er[12] + a3.y * er[13] + a3.z * er[14] + a3.w * er[15];
        v[s] = fmaxf(dot, 0.0f);
        m = fmaxf(m, v[s]);
    }
#pragma unroll
    for (int off = 1; off < 64; off <<= 1) m = fmaxf(m, __shfl_xor(m, off));
    const int wave = t >> 6, lane = t & 63;
    if (lane == 0) redm[wave] = m;
    __syncthreads();
    m = fmaxf(fmaxf(redm[0], redm[1]), fmaxf(redm[2], redm[3]));

    float sum = 0.0f;
#pragma unroll
    for (int s = 0; s < 16; ++s) {
        v[s] = expf(v[s] - m);
        sum += v[s];
    }
#pragma unroll
    for (int off = 1; off < 64; off <<= 1) sum += __shfl_xor(sum, off);
    if (lane == 0) reds[wave] = sum;
    __syncthreads();
    const float rinv = 1.0f / (reds[0] + reds[1] + reds[2] + reds[3]);
#pragma unroll
    for (int s = 0; s < 16; ++s)
        Af[(size_t)i * NN + s * 256 + t] = f2h_bits(v[s] * rinv);
}

// ---------------------------------------------------------------------------
// Kernel 2: transpose X [B,N,C] -> Xtf [BC=b*64+c][N] fp16
// ---------------------------------------------------------------------------
__global__ __launch_bounds__(256) void pack_xt(const float* __restrict__ X,
                                               u16* __restrict__ Xtf) {
    const int n0 = blockIdx.x * 64;
    const int b  = blockIdx.y;
    const int t  = threadIdx.x;
    __shared__ float tx[64][68];
    const float* src = X + (size_t)b * (NN * CC) + (size_t)n0 * CC;
#pragma unroll
    for (int l = 0; l < 4; ++l) {
        const int idx = t + l * 256;   // 1024 float4 chunks
        const int r = idx >> 4;
        const int c4 = (idx & 15) * 4;
        float4 v = *(const float4*)(src + r * CC + c4);
        tx[r][c4 + 0] = v.x; tx[r][c4 + 1] = v.y;
        tx[r][c4 + 2] = v.z; tx[r][c4 + 3] = v.w;
    }
    __syncthreads();
#pragma unroll
    for (int l = 0; l < 2; ++l) {
        const int idx = t + l * 256;   // 512 chunks of 8 fp16
        const int c = idx >> 3;
        const int n8 = (idx & 7) * 8;
        u32 hw[4];
#pragma unroll
        for (int jp = 0; jp < 4; ++jp) {
            float v0 = tx[n8 + 2 * jp][c];
            float v1 = tx[n8 + 2 * jp + 1][c];
            hw[jp] = (u32)f2h_bits(v0) | ((u32)f2h_bits(v1) << 16);
        }
        const size_t off = (size_t)(b * 64 + c) * NN + n0 + n8;
        *(uint4*)(Xtf + off) = make_uint4(hw[0], hw[1], hw[2], hw[3]);
    }
}

// ---------------------------------------------------------------------------
// Kernel 3: fp16 MFMA GEMM. Tile 256x128, BK=32, 4-way K-SPLIT (K=1024/blk),
//   512 thr (8 waves 4Mx2N, 64x64/wave), DOUBLE-buffered LDS 48KB (rd11's
//   single-buffer lost 40% staging BW -> restored rd10 loop shape).
//   grid 512 = 2 blocks/CU; staged 384 MB/GEMM (vs 1.07GB rd10).
// ---------------------------------------------------------------------------
#define GLOAD16(g, l) __builtin_amdgcn_global_load_lds( \
    (const __attribute__((address_space(1))) unsigned int*)(g), \
    (__attribute__((address_space(3))) unsigned int*)(l), 16, 0, 0)

__global__ __launch_bounds__(512) void gemm_ks(
    const u16* __restrict__ Af, const u16* __restrict__ Bf,
    float* __restrict__ P0, float* __restrict__ P1,
    float* __restrict__ P2, float* __restrict__ P3)
{
    // uint4 chunks per buffer: [A 0..1023][B 1024..1535]
    __shared__ uint4 lds[2][1536];   // 48 KB
    const int t = threadIdx.x;

    const int lin  = blockIdx.x;
    const int col0 = (lin & 7) * 128;           // 8 col panels = XCD id (rr)
    const int row0 = ((lin >> 3) & 15) * 256;   // 16 M panels
    const int kq   = lin >> 7;                  // 0..3 K-quarter
    const int kbase = kq * 1024;
    float* __restrict__ Pf = (kq & 2) ? ((kq & 1) ? P3 : P2)
                                      : ((kq & 1) ? P1 : P0);

    // staging: chunk j -> row=j>>2, slot=j&3; source slot inverse-swizzled.
    // A: 1024 chunks (rows 0..255): j0=t, j1=t+512. B: 512 chunks: jb=t.
    const int j0 = t, j1 = t + 512;
    const int r0 = j0 >> 2, r1 = j1 >> 2;
    const int s0 = (j0 & 3) ^ ((j0 >> 3) & 3);
    const int s1 = (j1 & 3) ^ ((j1 >> 3) & 3);
    const size_t aoff0 = (size_t)(row0 + r0) * NN + 8 * s0 + kbase;
    const size_t aoff1 = (size_t)(row0 + r1) * NN + 8 * s1 + kbase;
    const size_t boff0 = (size_t)(col0 + r0) * NN + 8 * s0 + kbase;

    const int lane = t & 63, g = lane >> 4, lr = lane & 15;
    const int wm = t >> 7;            // 0..3
    const int wn = (t >> 6) & 1;      // 0..1
    int ia[4], ib[4];
#pragma unroll
    for (int i = 0; i < 4; ++i) {
        const int ra = wm * 64 + 16 * i + lr;
        ia[i] = ra * 4 + (g ^ ((ra >> 1) & 3));
        const int rb = wn * 64 + 16 * i + lr;
        ib[i] = 1024 + rb * 4 + (g ^ ((rb >> 1) & 3));
    }

    f32x4 acc[4][4];
    const f32x4 zz = {0.f, 0.f, 0.f, 0.f};
#pragma unroll
    for (int i = 0; i < 4; ++i)
#pragma unroll
        for (int p = 0; p < 4; ++p) acc[i][p] = zz;

#define STAGE(bf, kt) do { \
        GLOAD16(Af + aoff0 + (kt), &lds[bf][j0]); \
        GLOAD16(Af + aoff1 + (kt), &lds[bf][j1]); \
        GLOAD16(Bf + boff0 + (kt), &lds[bf][1024 + j0]); \
    } while (0)

    STAGE(0, 0);
    __syncthreads();

#pragma unroll 2
    for (int kt = 0; kt < 1024; kt += 32) {
        const int cur = (kt >> 5) & 1;
        if (kt + 32 < 1024) STAGE(cur ^ 1, kt + 32);

        f16x8 a[4], b[4];
#pragma unroll
        for (int i = 0; i < 4; ++i) {
            a[i] = *(const f16x8*)&lds[cur][ia[i]];
            b[i] = *(const f16x8*)&lds[cur][ib[i]];
        }
#pragma unroll
        for (int i = 0; i < 4; ++i)
#pragma unroll
            for (int p = 0; p < 4; ++p)
                acc[i][p] = __builtin_amdgcn_mfma_f32_16x16x32_f16(a[i], b[p], acc[i][p], 0, 0, 0);
        __syncthreads();
    }

    // epilogue: f32 partial. C/D layout col=lane&15, row=(lane>>4)*4+q.
#pragma unroll
    for (int i = 0; i < 4; ++i)
#pragma unroll
        for (int p = 0; p < 4; ++p) {
            const int mb = row0 + wm * 64 + 16 * i + g * 4;
            const int c  = col0 + wn * 64 + 16 * p + lr;
#pragma unroll
            for (int q = 0; q < 4; ++q)
                Pf[(size_t)(mb + q) * BC + c] = acc[i][p][q];
        }
#undef STAGE
}

// ---------------------------------------------------------------------------
// Kernel 3b: sum 4 partials + transpose -> G1tf fp16 (into Xtf slot).
// ---------------------------------------------------------------------------
__global__ __launch_bounds__(256) void reduce_t4(const float* __restrict__ P0,
                                                 const float* __restrict__ P1,
                                                 const float* __restrict__ P2,
                                                 const float* __restrict__ P3,
                                                 u16* __restrict__ G1tf) {
    const int n0 = blockIdx.x * 64;
    const int c0 = blockIdx.y * 64;
    const int t  = threadIdx.x;
    __shared__ float tx[64][68];
#pragma unroll
    for (int l = 0; l < 4; ++l) {
        const int idx = t + l * 256;
        const int r = idx >> 4;
        const int c4 = (idx & 15) * 4;
        const size_t off = (size_t)(n0 + r) * BC + c0 + c4;
        float4 v0 = *(const float4*)(P0 + off);
        float4 v1 = *(const float4*)(P1 + off);
        float4 v2 = *(const float4*)(P2 + off);
        float4 v3 = *(const float4*)(P3 + off);
        tx[r][c4 + 0] = (v0.x + v1.x) + (v2.x + v3.x);
        tx[r][c4 + 1] = (v0.y + v1.y) + (v2.y + v3.y);
        tx[r][c4 + 2] = (v0.z + v1.z) + (v2.z + v3.z);
        tx[r][c4 + 3] = (v0.w + v1.w) + (v2.w + v3.w);
    }
    __syncthreads();
#pragma unroll
    for (int l = 0; l < 2; ++l) {
        const int idx = t + l * 256;
        const int c = idx >> 3;
        const int n8 = (idx & 7) * 8;
        u32 hw[4];
#pragma unroll
        for (int jp = 0; jp < 4; ++jp) {
            float v0 = tx[n8 + 2 * jp][c];
            float v1 = tx[n8 + 2 * jp + 1][c];
            hw[jp] = (u32)f2h_bits(v0) | ((u32)f2h_bits(v1) << 16);
        }
        const size_t off = (size_t)(c0 + c) * NN + n0 + n8;
        *(uint4*)(G1tf + off) = make_uint4(hw[0], hw[1], hw[2], hw[3]);
    }
}

// ---------------------------------------------------------------------------
// Kernel 3c: G2f = P0+P1+P2+P3, in-place into P0.
// ---------------------------------------------------------------------------
__global__ __launch_bounds__(256) void reduce_lin4(float* __restrict__ P0,
                                                   const float* __restrict__ P1,
                                                   const float* __restrict__ P2,
                                                   const float* __restrict__ P3) {
    const int idx = blockIdx.x * 256 + threadIdx.x;   // NN*BC/4 float4s
    float4 a = ((const float4*)P0)[idx];
    float4 b = ((const float4*)P1)[idx];
    float4 c = ((const float4*)P2)[idx];
    float4 d = ((const float4*)P3)[idx];
    ((float4*)P0)[idx] = make_float4((a.x + b.x) + (c.x + d.x),
                                     (a.y + b.y) + (c.y + d.y),
                                     (a.z + b.z) + (c.z + d.z),
                                     (a.w + b.w) + (c.w + d.w));
}

// ---------------------------------------------------------------------------
// Kernel 4: 4 nodes x 32-o-half per block, 512 threads (rd10 structure).
//   G1 read from G1tf (fp16) slice, converted to bf16 for the xgb store.
// ---------------------------------------------------------------------------
__global__ __launch_bounds__(512) void final_apply3(const float* __restrict__ X,
                                                    const float* __restrict__ E,
                                                    const u16* __restrict__ G1tf,
                                                    const float* __restrict__ G2,
                                                    const float* __restrict__ wp,
                                                    const float* __restrict__ bp,
                                                    float* __restrict__ out) {
    const int ng = blockIdx.x;         // nodes ng*4 .. ng*4+3
    const int oh = blockIdx.y;         // o-half
    const int o0 = oh * 32;
    const int t  = threadIdx.x;
    __shared__ float Wl[4][192][32];       // 98304 B
    __shared__ u16   xgb[4][3][16][68];    // 26112 B
    __shared__ float esh[4][16];

    if (t < 64) esh[t >> 4][t & 15] = E[(ng * 4 + (t >> 4)) * DD + (t & 15)];

    // ---- stage xg k=0 (X) and k=2 (2*G2-X): 2048 float4-chunks, 4/thread ----
#pragma unroll
    for (int l = 0; l < 4; ++l) {
        const int c = t + l * 512;
        const int kk = c >> 10;          // 0: X, 1: G2-branch
        const int j  = (c >> 8) & 3;
        const int b  = (c >> 4) & 15;
        const int i4 = c & 15;
        const int n_g = ng * 4 + j;
        float4 v;
        if (kk == 0) {
            v = *(const float4*)(X + ((size_t)b * NN + n_g) * CC + i4 * 4);
        } else {
            float4 g2 = *(const float4*)(G2 + (size_t)n_g * BC + b * 64 + i4 * 4);
            float4 x  = *(const float4*)(X + ((size_t)b * NN + n_g) * CC + i4 * 4);
            v = make_float4(2.f * g2.x - x.x, 2.f * g2.y - x.y,
                            2.f * g2.z - x.z, 2.f * g2.w - x.w);
        }
        const int ks = (kk == 0) ? 0 : 2;
        u32 w0 = (u32)f2bf(v.x) | ((u32)f2bf(v.y) << 16);
        u32 w1 = (u32)f2bf(v.z) | ((u32)f2bf(v.w) << 16);
        *(uint2*)&xgb[j][ks][b][i4 * 4] = make_uint2(w0, w1);
    }
    // ---- stage xg k=1: G1tf slice [bc][4ng..4ng+3], 1024 rows, 2/thread ----
#pragma unroll
    for (int l = 0; l < 2; ++l) {
        const int row = t + l * 512;     // bc = b*64 + i
        const int b = row >> 6;
        const int i = row & 63;
        const ushort4 g = *(const ushort4*)(G1tf + (size_t)row * NN + 4 * ng);
        xgb[0][1][b][i] = f2bf(h2f(g.x));
        xgb[1][1][b][i] = f2bf(h2f(g.y));
        xgb[2][1][b][i] = f2bf(h2f(g.z));
        xgb[3][1][b][i] = f2bf(h2f(g.w));
    }
    __syncthreads();

    // ---- W-gen: 1536 (ki,o4) tasks, 3/thread; wp read ONCE for 4 nodes ----
    float er[4][16];
#pragma unroll
    for (int j = 0; j < 4; ++j)
#pragma unroll
        for (int d = 0; d < DD; ++d) er[j][d] = esh[j][d];

    const float4* wp4 = (const float4*)wp;
#pragma unroll
    for (int l = 0; l < 3; ++l) {
        const int tk = t + l * 512;
        const int ki = tk >> 3;          // 0..191
        const int q  = tk & 7;
        float4 a0 = make_float4(0.f, 0.f, 0.f, 0.f);
        float4 a1 = a0, a2 = a0, a3 = a0;
#pragma unroll
        for (int d = 0; d < DD; ++d) {
            float4 v = wp4[d * 3072 + ki * 16 + oh * 8 + q];
            a0.x += er[0][d] * v.x; a0.y += er[0][d] * v.y; a0.z += er[0][d] * v.z; a0.w += er[0][d] * v.w;
            a1.x += er[1][d] * v.x; a1.y += er[1][d] * v.y; a1.z += er[1][d] * v.z; a1.w += er[1][d] * v.w;
            a2.x += er[2][d] * v.x; a2.y += er[2][d] * v.y; a2.z += er[2][d] * v.z; a2.w += er[2][d] * v.w;
            a3.x += er[3][d] * v.x; a3.y += er[3][d] * v.y; a3.z += er[3][d] * v.z; a3.w += er[3][d] * v.w;
        }
        *(float4*)&Wl[0][ki][q * 4] = a0;
        *(float4*)&Wl[1][ki][q * 4] = a1;
        *(float4*)&Wl[2][ki][q * 4] = a2;
        *(float4*)&Wl[3][ki][q * 4] = a3;
    }
    __syncthreads();

    // ---- apply: thread -> (n = t>>7, b = (t>>3)&15, o4 = t&7) ----
    const int o4 = t & 7;
    const int b  = (t >> 3) & 15;
    const int n  = t >> 7;
    const int n_g = ng * 4 + n;

    const float4* bp4 = (const float4*)bp;
    float4 acc = make_float4(0.f, 0.f, 0.f, 0.f);
#pragma unroll
    for (int d = 0; d < DD; ++d) {
        const float e = esh[n][d];
        float4 bv = bp4[d * 16 + oh * 8 + o4];
        acc.x += e * bv.x; acc.y += e * bv.y; acc.z += e * bv.z; acc.w += e * bv.w;
    }
#pragma unroll
    for (int k = 0; k < 3; ++k) {
#pragma unroll
        for (int i2 = 0; i2 < 32; ++i2) {
            const u32 xu = *(const u32*)&xgb[n][k][b][i2 * 2];
            const float x0 = bf2f((u16)(xu & 0xffffu));
            const float x1 = bf2f((u16)(xu >> 16));
            const float4 w0 = *(const float4*)&Wl[n][k * 64 + i2 * 2][o4 * 4];
            const float4 w1 = *(const float4*)&Wl[n][k * 64 + i2 * 2 + 1][o4 * 4];
            acc.x += x0 * w0.x + x1 * w1.x;
            acc.y += x0 * w0.y + x1 * w1.y;
            acc.z += x0 * w0.z + x1 * w1.z;
            acc.w += x0 * w0.w + x1 * w1.w;
        }
    }
    *(float4*)(out + ((size_t)b * NN + n_g) * OO + o0 + o4 * 4) = acc;
}

// ---------------------------------------------------------------------------
extern "C" void kernel_launch(void* const* d_in, const int* in_sizes, int n_in,
                              void* d_out, int out_size, void* d_ws, size_t ws_size,
                              hipStream_t stream) {
    const float* X  = (const float*)d_in[0];   // [16,4096,64]
    const float* E  = (const float*)d_in[1];   // [4096,16]
    const float* wp = (const float*)d_in[3];   // [16,3,64,64]
    const float* bp = (const float*)d_in[4];   // [16,64]
    float* out = (float*)d_out;                // [16,4096,64] = 16 MB

    // ws layout (88 MB):
    u16* Af  = (u16*)d_ws;                         // 32 MB fp16 A
    u16* Xtf = Af + (size_t)NN * NN;               //  8 MB (-> G1tf after reduce_t4)
    float* P0 = (float*)(Xtf + (size_t)BC * NN);   // 16 MB (-> G2f after reduce_lin4)
    float* P1 = P0 + (size_t)NN * BC;              // 16 MB
    float* P2 = P1 + (size_t)NN * BC;              // 16 MB
    float* Pd = out;                               // d_out as 4th partial (dead
                                                   //   until final, fully consumed)

    softmax_adj<<<NN, 256, 0, stream>>>(E, Af);
    pack_xt<<<dim3(NN / 64, BB), 256, 0, stream>>>(X, Xtf);
    // GEMM1: G1 = A @ Xt^T  (4 K-quarter partials -> transpose G1tf)
    gemm_ks<<<512, 512, 0, stream>>>(Af, Xtf, P0, P1, P2, Pd);
    reduce_t4<<<dim3(NN / 64, BC / 64), 256, 0, stream>>>(P0, P1, P2, Pd, Xtf);
    // GEMM2: G2 = A @ G1t^T
    gemm_ks<<<512, 512, 0, stream>>>(Af, Xtf, P0, P1, P2, Pd);
    reduce_lin4<<<(NN * BC / 4) / 256, 256, 0, stream>>>(P0, P1, P2, Pd);
    final_apply3<<<dim3(NN / 4, 2), 512, 0, stream>>>(X, E, Xtf, P0, wp, bp, out);
}